// Round 1
// baseline (1620.373 us; speedup 1.0000x reference)
//
#include <hip/hip_runtime.h>
#include <float.h>

// Flash-attention forward for: out = max_s(softmax(A A^T) A) @ W^T + b
// A = emb_table[x[b]] (2048 x 512), B=32 batches, then 512->2 FC.
// bf16 MFMA (16x16x32), online softmax, pooled-max via ordered-uint atomics.

typedef __attribute__((ext_vector_type(8))) short bf16x8;   // 8 bf16 = 4 VGPRs
typedef __attribute__((ext_vector_type(4))) float f32x4;    // MFMA C/D frag
typedef __attribute__((ext_vector_type(4))) short s16x4;    // 8B LDS write

#define LDK 520   // shorts per Ktile row (512 + 8 pad -> bank shift 4/row)
#define LDV 40    // shorts per Vt row   (32 + 8 pad, 80B rows, 16B aligned)
#define LDP 40    // shorts per Ptile row

__device__ __forceinline__ short f2bf(float f) {   // RNE f32->bf16 (finite inputs)
  unsigned u = __float_as_uint(f);
  unsigned r = (u + 0x7fffu + ((u >> 16) & 1u)) >> 16;
  return (short)r;
}
__device__ __forceinline__ unsigned ordf(float f) { // monotonic float->uint
  unsigned u = __float_as_uint(f);
  return (u & 0x80000000u) ? ~u : (u | 0x80000000u);
}
__device__ __forceinline__ float unordf(unsigned e) {
  unsigned u = (e & 0x80000000u) ? (e ^ 0x80000000u) : ~e;
  return __uint_as_float(u);
}

extern "C" __global__ __launch_bounds__(256, 2)
void attn_flash(const int* __restrict__ xp, const float* __restrict__ emb,
                unsigned* __restrict__ pooled) {
  __shared__ __align__(16) short lds_k[32 * LDK];    // K tile, row-major [key][e]
  __shared__ __align__(16) short lds_vt[512 * LDV];  // V tile, transposed [e][key]
  __shared__ __align__(16) short lds_p[64 * LDP];    // P tile [q][key]

  const int t = threadIdx.x;
  const int l = t & 63;
  const int w = t >> 6;          // wave 0..3, owns queries w*16..w*16+15
  const int b = blockIdx.y;      // batch
  const int q0 = blockIdx.x * 64;
  const int L = l & 15;          // lane%16: A-row / B-col / C-col index
  const int g = l >> 4;          // lane group: k-chunk / C-row group

  // ---- Q fragments: 16 queries x 512 E per wave, kept in registers ----
  bf16x8 qf[16];
  {
    int q = q0 + w * 16 + L;
    const float* qrow = emb + (long)xp[b * 2048 + q] * 512;
#pragma unroll
    for (int ec = 0; ec < 16; ++ec) {
      int e0 = ec * 32 + 8 * g;
      float4 fa = *(const float4*)(qrow + e0);
      float4 fb = *(const float4*)(qrow + e0 + 4);
      bf16x8 v;
      v[0] = f2bf(fa.x); v[1] = f2bf(fa.y); v[2] = f2bf(fa.z); v[3] = f2bf(fa.w);
      v[4] = f2bf(fb.x); v[5] = f2bf(fb.y); v[6] = f2bf(fb.z); v[7] = f2bf(fb.w);
      qf[ec] = v;
    }
  }

  f32x4 acc[32];                 // attended accumulators: 16q x 512e per wave
#pragma unroll
  for (int nt = 0; nt < 32; ++nt) acc[nt] = (f32x4){0.f, 0.f, 0.f, 0.f};
  float mrun[4] = {-FLT_MAX, -FLT_MAX, -FLT_MAX, -FLT_MAX};
  float lrun[4] = {0.f, 0.f, 0.f, 0.f};

  for (int kt = 0; kt < 64; ++kt) {
    __syncthreads();             // previous tile fully consumed
    // ---- stage 32-key tile; two halves fill the two layouts ----
    if (t < 128) {
      // waves 0-1: row-major Ktile[key][e]; iter i = key, coalesced 2KB row reads
#pragma unroll 4
      for (int i = 0; i < 32; ++i) {
        const float* krow = emb + (long)xp[b * 2048 + kt * 32 + i] * 512;
        float4 f = *(const float4*)(krow + 4 * t);
        s16x4 v = { f2bf(f.x), f2bf(f.y), f2bf(f.z), f2bf(f.w) };
        *(s16x4*)&lds_k[i * LDK + 4 * t] = v;
      }
    } else {
      // waves 2-3: transposed Vt[e][key]; per key 64-lane coalesced column reads
      const int u = t - 128;
      const int lane_ = u & 63;
      const int half = u >> 6;
#pragma unroll 2
      for (int kq = 0; kq < 8; ++kq) {
        const int kbase = b * 2048 + kt * 32 + kq * 4;
        const float* r0 = emb + (long)xp[kbase + 0] * 512;
        const float* r1 = emb + (long)xp[kbase + 1] * 512;
        const float* r2 = emb + (long)xp[kbase + 2] * 512;
        const float* r3 = emb + (long)xp[kbase + 3] * 512;
#pragma unroll
        for (int seg = 0; seg < 4; ++seg) {
          int e = lane_ + 64 * (seg + 4 * half);
          s16x4 v = { f2bf(r0[e]), f2bf(r1[e]), f2bf(r2[e]), f2bf(r3[e]) };
          *(s16x4*)&lds_vt[e * LDV + 4 * kq] = v;
        }
      }
    }
    __syncthreads();

    // ---- QK^T: D[q][key], two 16-col n-tiles, contraction E=512 ----
    f32x4 s0 = {0.f, 0.f, 0.f, 0.f}, s1 = {0.f, 0.f, 0.f, 0.f};
#pragma unroll
    for (int ec = 0; ec < 16; ++ec) {
      bf16x8 k0 = *(const bf16x8*)&lds_k[L * LDK + ec * 32 + 8 * g];
      bf16x8 k1 = *(const bf16x8*)&lds_k[(L + 16) * LDK + ec * 32 + 8 * g];
      s0 = __builtin_amdgcn_mfma_f32_16x16x32_bf16(qf[ec], k0, s0, 0, 0, 0);
      s1 = __builtin_amdgcn_mfma_f32_16x16x32_bf16(qf[ec], k1, s1, 0, 0, 0);
    }

    // ---- online softmax; lane owns rows 4g+r, cols nt*16+L ----
    float p0[4], p1[4], sc[4];
#pragma unroll
    for (int r = 0; r < 4; ++r) {
      float v = fmaxf(s0[r], s1[r]);
      v = fmaxf(v, __shfl_xor(v, 1, 64));
      v = fmaxf(v, __shfl_xor(v, 2, 64));
      v = fmaxf(v, __shfl_xor(v, 4, 64));
      v = fmaxf(v, __shfl_xor(v, 8, 64));
      float nm = fmaxf(mrun[r], v);
      sc[r] = expf(mrun[r] - nm);          // ==1 when max unchanged, 0 on first tile
      p0[r] = expf(s0[r] - nm);
      p1[r] = expf(s1[r] - nm);
      float rs = p0[r] + p1[r];
      rs += __shfl_xor(rs, 1, 64);
      rs += __shfl_xor(rs, 2, 64);
      rs += __shfl_xor(rs, 4, 64);
      rs += __shfl_xor(rs, 8, 64);
      lrun[r] = lrun[r] * sc[r] + rs;
      mrun[r] = nm;
    }
    if (__any(sc[0] < 1.f || sc[1] < 1.f || sc[2] < 1.f || sc[3] < 1.f)) {
      f32x4 sv = { sc[0], sc[1], sc[2], sc[3] };
#pragma unroll
      for (int nt = 0; nt < 32; ++nt) acc[nt] *= sv;
    }

    // ---- P (bf16) via LDS to convert C-layout -> A-frag layout ----
#pragma unroll
    for (int r = 0; r < 4; ++r) {
      int row = w * 16 + g * 4 + r;
      lds_p[row * LDP + L]      = f2bf(p0[r]);
      lds_p[row * LDP + 16 + L] = f2bf(p1[r]);
    }
    asm volatile("s_waitcnt lgkmcnt(0)" ::: "memory");  // wave-private P tile ready

    // ---- PV: acc[q][e] += P[q][k] * V[k][e], 32 n-tiles of 16 e ----
    bf16x8 pf = *(const bf16x8*)&lds_p[(w * 16 + L) * LDP + 8 * g];
#pragma unroll
    for (int nt = 0; nt < 32; ++nt) {
      bf16x8 vf = *(const bf16x8*)&lds_vt[(nt * 16 + L) * LDV + 8 * g];
      acc[nt] = __builtin_amdgcn_mfma_f32_16x16x32_bf16(pf, vf, acc[nt], 0, 0, 0);
    }
  }

  // ---- epilogue: normalize, max over the block's 64 queries, global atomicMax ----
  __syncthreads();
  float inv[4];
#pragma unroll
  for (int r = 0; r < 4; ++r) inv[r] = 1.f / lrun[r];
  float* rbuf = (float*)lds_k;   // reuse Ktile region (post-sync)
#pragma unroll
  for (int nt = 0; nt < 32; ++nt) {
    f32x4 a = acc[nt];
    float c = fmaxf(fmaxf(a[0] * inv[0], a[1] * inv[1]),
                    fmaxf(a[2] * inv[2], a[3] * inv[3]));
    c = fmaxf(c, __shfl_xor(c, 16, 64));   // combine row groups
    c = fmaxf(c, __shfl_xor(c, 32, 64));
    if (g == 0) rbuf[w * 512 + nt * 16 + L] = c;
  }
  __syncthreads();
  for (int j = t; j < 512; j += 256) {
    float v = fmaxf(fmaxf(rbuf[j], rbuf[512 + j]),
                    fmaxf(rbuf[1024 + j], rbuf[1536 + j]));
    atomicMax(&pooled[b * 512 + j], ordf(v));
  }
}

extern "C" __global__ void fc_small(const unsigned* __restrict__ pooled,
                                    const float* __restrict__ fw,
                                    const float* __restrict__ fb,
                                    float* __restrict__ out) {
  int t = threadIdx.x;
  if (t >= 64) return;
  int bb = t >> 1, c = t & 1;
  float s = fb[c];
  for (int e = 0; e < 512; ++e)
    s += unordf(pooled[bb * 512 + e]) * fw[c * 512 + e];
  out[t] = s;   // t == bb*2 + c, row-major (32,2)
}

extern "C" void kernel_launch(void* const* d_in, const int* in_sizes, int n_in,
                              void* d_out, int out_size, void* d_ws, size_t ws_size,
                              hipStream_t stream) {
  const int* xp    = (const int*)d_in[0];     // token ids (32,2048), int32
  const float* emb = (const float*)d_in[1];   // (50257,512) f32
  const float* fw  = (const float*)d_in[2];   // (2,512) f32
  const float* fb  = (const float*)d_in[3];   // (2,) f32
  unsigned* pooled = (unsigned*)d_ws;         // 32*512 ordered-uint running max

  hipMemsetAsync(pooled, 0, 32 * 512 * sizeof(unsigned), stream);  // == -inf
  attn_flash<<<dim3(32, 32), 256, 0, stream>>>(xp, emb, pooled);
  fc_small<<<1, 64, 0, stream>>>(pooled, fw, fb, (float*)d_out);
}

// Round 2
// 679.534 us; speedup vs baseline: 2.3845x; 2.3845x over previous
//
#include <hip/hip_runtime.h>
#include <float.h>

// out = max_s(softmax(A A^T) A) @ W^T + b, A = emb[x[b]] (2048x512), B=32.
// R2: prep kernel materializes frag-ordered bf16 K/V operand arrays in ws;
// attn kernel = linear global_load_lds staging + conflict-free ds_read_b128
// frag reads + 16x16x32 bf16 MFMA flash loop. Fallback to R1 path if ws small.

typedef __attribute__((ext_vector_type(8))) short short8;   // 8 bf16 = 4 VGPRs
typedef __attribute__((ext_vector_type(4))) float f32x4;    // MFMA C/D frag
typedef __attribute__((ext_vector_type(4))) short s16x4;

__device__ __forceinline__ short f2bf(float f) {   // RNE f32->bf16 (finite)
  unsigned u = __float_as_uint(f);
  unsigned r = (u + 0x7fffu + ((u >> 16) & 1u)) >> 16;
  return (short)r;
}
__device__ __forceinline__ unsigned ordf(float f) { // monotonic float->uint
  unsigned u = __float_as_uint(f);
  return (u & 0x80000000u) ? ~u : (u | 0x80000000u);
}
__device__ __forceinline__ float unordf(unsigned e) {
  unsigned u = (e & 0x80000000u) ? (e ^ 0x80000000u) : ~e;
  return __uint_as_float(u);
}
__device__ __forceinline__ void gload16(const void* g, void* s) {
  __builtin_amdgcn_global_load_lds((const __attribute__((address_space(1))) void*)g,
                                   (__attribute__((address_space(3))) void*)s,
                                   16, 0, 0);
}

// ---------------- prep: build frag-ordered bf16 operands ----------------
// Kf chunk (b,kt): 32 frags (f=ec*2+nt) x 64 lanes x 16B:
//   lane l holds A[key=kt*32+16*nt+(l&15)][e=ec*32+(l>>4)*8 .. +7]
// Vf chunk (b,kt): 32 frags (nt) x 64 lanes x 16B:
//   lane l holds A[key=kt*32+(l>>4)*8+j][e=nt*16+(l&15)], j=0..7
extern "C" __global__ __launch_bounds__(256)
void prep_frag(const int* __restrict__ xp, const float* __restrict__ emb,
               short* __restrict__ Kf, short* __restrict__ Vf) {
  __shared__ __align__(16) short ls[32 * 520];   // A tile bf16, padded rows
  const int t = threadIdx.x;
  const int kt = blockIdx.x, b = blockIdx.y;
  {
    const int r = t >> 3, seg = t & 7;           // 32 rows x 8 segs of 64 floats
    const float* src = emb + (long)xp[b * 2048 + kt * 32 + r] * 512 + seg * 64;
    short* dst = ls + r * 520 + seg * 64;
#pragma unroll
    for (int i = 0; i < 8; ++i) {
      float4 fa = *(const float4*)(src + i * 8);
      float4 fb = *(const float4*)(src + i * 8 + 4);
      short8 v = { f2bf(fa.x), f2bf(fa.y), f2bf(fa.z), f2bf(fa.w),
                   f2bf(fb.x), f2bf(fb.y), f2bf(fb.z), f2bf(fb.w) };
      *(short8*)(dst + i * 8) = v;
    }
  }
  __syncthreads();
  const long chunk = ((long)b * 64 + kt) * 2048;   // in 16B granules
#pragma unroll
  for (int rr = 0; rr < 8; ++rr) {                 // Kf: contiguous row slices
    int j = rr * 256 + t;
    int f = j >> 6, l = j & 63;
    int key = ((f & 1) << 4) + (l & 15);
    int e0 = (f >> 1) * 32 + (l >> 4) * 8;
    *(short8*)(Kf + (chunk + j) * 8) = *(const short8*)(ls + key * 520 + e0);
  }
#pragma unroll
  for (int rr = 0; rr < 8; ++rr) {                 // Vf: 8-row column gather
    int j = rr * 256 + t;
    int nt = j >> 6, l = j & 63;
    const short* col = ls + ((l >> 4) * 8) * 520 + nt * 16 + (l & 15);
    short8 v = { col[0], col[520], col[1040], col[1560],
                 col[2080], col[2600], col[3120], col[3640] };
    *(short8*)(Vf + (chunk + j) * 8) = v;
  }
}

// ---------------- attention (frag-ordered inputs) ----------------
extern "C" __global__ __launch_bounds__(256, 2)
void attn2(const short* __restrict__ Kf, const short* __restrict__ Vf,
           unsigned* __restrict__ pooled) {
  __shared__ __align__(16) short lk[16384];   // 32KB K tile (32 frags)
  __shared__ __align__(16) short lv[16384];   // 32KB V tile (32 frags)
  __shared__ __align__(16) short lp[64 * 40]; // P tile [q][key], padded

  const int t = threadIdx.x, l = t & 63, w = t >> 6;
  const int n = blockIdx.x;
  const int b = (n & 7) + ((n >> 8) << 3);    // batch -> XCD pinning (n%8==b%8)
  const int qt = (n >> 3) & 31;               // 64-query tile
  const int L = l & 15, g = l >> 4;

  const short* Kc = Kf + ((long)b * 64) * 16384;  // batch bases (shorts)
  const short* Vc = Vf + ((long)b * 64) * 16384;

  // Q frags: wave w owns queries qt*64 + w*16 + L; read from Kf chunks
  short8 qf[16];
  {
    const short* qc = Kc + (long)(qt * 2 + (w >> 1)) * 16384;
#pragma unroll
    for (int ec = 0; ec < 16; ++ec)
      qf[ec] = *(const short8*)(qc + ((ec * 2 + (w & 1)) * 64 + l) * 8);
  }

  f32x4 acc[32];
#pragma unroll
  for (int nt = 0; nt < 32; ++nt) acc[nt] = (f32x4){0.f, 0.f, 0.f, 0.f};
  float mrun[4] = {-FLT_MAX, -FLT_MAX, -FLT_MAX, -FLT_MAX};
  float lrun[4] = {0.f, 0.f, 0.f, 0.f};

  for (int kt = 0; kt < 64; ++kt) {
    const short* kg = Kc + (long)kt * 16384;
    const short* vg = Vc + (long)kt * 16384;
    // ---- stage both tiles: 16 linear global_load_lds dwordx4 / thread ----
#pragma unroll
    for (int it = 0; it < 8; ++it) {
      int sw = it * 256 + w * 64;            // wave-uniform slot base
      gload16(kg + (sw + l) * 8, lk + sw * 8);
    }
#pragma unroll
    for (int it = 0; it < 8; ++it) {
      int sw = it * 256 + w * 64;
      gload16(vg + (sw + l) * 8, lv + sw * 8);
    }
    __syncthreads();                          // drains vmcnt; tiles ready

    // ---- QK^T: 32 frag reads + 32 MFMA ----
    f32x4 s0 = {0.f, 0.f, 0.f, 0.f}, s1 = {0.f, 0.f, 0.f, 0.f};
#pragma unroll
    for (int ec = 0; ec < 16; ++ec) {
      short8 k0 = *(const short8*)(lk + ((ec * 2 + 0) * 64 + l) * 8);
      short8 k1 = *(const short8*)(lk + ((ec * 2 + 1) * 64 + l) * 8);
      s0 = __builtin_amdgcn_mfma_f32_16x16x32_bf16(qf[ec], k0, s0, 0, 0, 0);
      s1 = __builtin_amdgcn_mfma_f32_16x16x32_bf16(qf[ec], k1, s1, 0, 0, 0);
    }

    // ---- online softmax; lane owns rows 4g+r, cols {L, 16+L} ----
    float p0[4], p1[4], sc[4];
#pragma unroll
    for (int r = 0; r < 4; ++r) {
      float v = fmaxf(s0[r], s1[r]);
      v = fmaxf(v, __shfl_xor(v, 1, 64));
      v = fmaxf(v, __shfl_xor(v, 2, 64));
      v = fmaxf(v, __shfl_xor(v, 4, 64));
      v = fmaxf(v, __shfl_xor(v, 8, 64));
      float nm = fmaxf(mrun[r], v);
      sc[r] = expf(mrun[r] - nm);
      p0[r] = expf(s0[r] - nm);
      p1[r] = expf(s1[r] - nm);
      float rs = p0[r] + p1[r];
      rs += __shfl_xor(rs, 1, 64);
      rs += __shfl_xor(rs, 2, 64);
      rs += __shfl_xor(rs, 4, 64);
      rs += __shfl_xor(rs, 8, 64);
      lrun[r] = lrun[r] * sc[r] + rs;
      mrun[r] = nm;
    }
    if (__any(sc[0] < 1.f || sc[1] < 1.f || sc[2] < 1.f || sc[3] < 1.f)) {
      f32x4 sv = { sc[0], sc[1], sc[2], sc[3] };
#pragma unroll
      for (int nt = 0; nt < 32; ++nt) acc[nt] *= sv;
    }

    // ---- P via LDS (C-layout -> A-frag layout), wave-private ----
#pragma unroll
    for (int r = 0; r < 4; ++r) {
      int row = w * 16 + g * 4 + r;
      lp[row * 40 + L]      = f2bf(p0[r]);
      lp[row * 40 + 16 + L] = f2bf(p1[r]);
    }
    asm volatile("s_waitcnt lgkmcnt(0)" ::: "memory");
    short8 pf = *(const short8*)(lp + (w * 16 + L) * 40 + 8 * g);

    // ---- PV: 32 frag reads + 32 MFMA ----
#pragma unroll
    for (int nt = 0; nt < 32; ++nt) {
      short8 vfr = *(const short8*)(lv + (nt * 64 + l) * 8);
      acc[nt] = __builtin_amdgcn_mfma_f32_16x16x32_bf16(pf, vfr, acc[nt], 0, 0, 0);
    }
    __syncthreads();                          // all reads done; buffers free
  }

  // ---- epilogue: normalize, block-max over 64 queries, global atomicMax ----
  float inv[4];
#pragma unroll
  for (int r = 0; r < 4; ++r) inv[r] = 1.f / lrun[r];
  float* rbuf = (float*)lk;                   // reuse K tile region
#pragma unroll
  for (int nt = 0; nt < 32; ++nt) {
    f32x4 a = acc[nt];
    float c = fmaxf(fmaxf(a[0] * inv[0], a[1] * inv[1]),
                    fmaxf(a[2] * inv[2], a[3] * inv[3]));
    c = fmaxf(c, __shfl_xor(c, 16, 64));
    c = fmaxf(c, __shfl_xor(c, 32, 64));
    if (g == 0) rbuf[w * 512 + nt * 16 + L] = c;
  }
  __syncthreads();
  for (int j = t; j < 512; j += 256) {
    float v = fmaxf(fmaxf(rbuf[j], rbuf[512 + j]),
                    fmaxf(rbuf[1024 + j], rbuf[1536 + j]));
    atomicMax(&pooled[b * 512 + j], ordf(v));
  }
}

// ---------------- R1 fallback (small ws) ----------------
#define LDK 520
#define LDV 40
#define LDP 40
extern "C" __global__ __launch_bounds__(256, 2)
void attn_fb(const int* __restrict__ xp, const float* __restrict__ emb,
             unsigned* __restrict__ pooled) {
  __shared__ __align__(16) short lds_k[32 * LDK];
  __shared__ __align__(16) short lds_vt[512 * LDV];
  __shared__ __align__(16) short lds_p[64 * LDP];
  const int t = threadIdx.x, l = t & 63, w = t >> 6;
  const int b = blockIdx.y;
  const int q0 = blockIdx.x * 64;
  const int L = l & 15, g = l >> 4;
  short8 qf[16];
  {
    int q = q0 + w * 16 + L;
    const float* qrow = emb + (long)xp[b * 2048 + q] * 512;
#pragma unroll
    for (int ec = 0; ec < 16; ++ec) {
      int e0 = ec * 32 + 8 * g;
      float4 fa = *(const float4*)(qrow + e0);
      float4 fb = *(const float4*)(qrow + e0 + 4);
      short8 v = { f2bf(fa.x), f2bf(fa.y), f2bf(fa.z), f2bf(fa.w),
                   f2bf(fb.x), f2bf(fb.y), f2bf(fb.z), f2bf(fb.w) };
      qf[ec] = v;
    }
  }
  f32x4 acc[32];
#pragma unroll
  for (int nt = 0; nt < 32; ++nt) acc[nt] = (f32x4){0.f, 0.f, 0.f, 0.f};
  float mrun[4] = {-FLT_MAX, -FLT_MAX, -FLT_MAX, -FLT_MAX};
  float lrun[4] = {0.f, 0.f, 0.f, 0.f};
  for (int kt = 0; kt < 64; ++kt) {
    __syncthreads();
    if (t < 128) {
#pragma unroll 4
      for (int i = 0; i < 32; ++i) {
        const float* krow = emb + (long)xp[b * 2048 + kt * 32 + i] * 512;
        float4 f = *(const float4*)(krow + 4 * t);
        s16x4 v = { f2bf(f.x), f2bf(f.y), f2bf(f.z), f2bf(f.w) };
        *(s16x4*)&lds_k[i * LDK + 4 * t] = v;
      }
    } else {
      const int u = t - 128, lane_ = u & 63, half = u >> 6;
#pragma unroll 2
      for (int kq = 0; kq < 8; ++kq) {
        const int kbase = b * 2048 + kt * 32 + kq * 4;
        const float* r0 = emb + (long)xp[kbase + 0] * 512;
        const float* r1 = emb + (long)xp[kbase + 1] * 512;
        const float* r2 = emb + (long)xp[kbase + 2] * 512;
        const float* r3 = emb + (long)xp[kbase + 3] * 512;
#pragma unroll
        for (int seg = 0; seg < 4; ++seg) {
          int e = lane_ + 64 * (seg + 4 * half);
          s16x4 v = { f2bf(r0[e]), f2bf(r1[e]), f2bf(r2[e]), f2bf(r3[e]) };
          *(s16x4*)&lds_vt[e * LDV + 4 * kq] = v;
        }
      }
    }
    __syncthreads();
    f32x4 s0 = {0.f, 0.f, 0.f, 0.f}, s1 = {0.f, 0.f, 0.f, 0.f};
#pragma unroll
    for (int ec = 0; ec < 16; ++ec) {
      short8 k0 = *(const short8*)&lds_k[L * LDK + ec * 32 + 8 * g];
      short8 k1 = *(const short8*)&lds_k[(L + 16) * LDK + ec * 32 + 8 * g];
      s0 = __builtin_amdgcn_mfma_f32_16x16x32_bf16(qf[ec], k0, s0, 0, 0, 0);
      s1 = __builtin_amdgcn_mfma_f32_16x16x32_bf16(qf[ec], k1, s1, 0, 0, 0);
    }
    float p0[4], p1[4], sc[4];
#pragma unroll
    for (int r = 0; r < 4; ++r) {
      float v = fmaxf(s0[r], s1[r]);
      v = fmaxf(v, __shfl_xor(v, 1, 64));
      v = fmaxf(v, __shfl_xor(v, 2, 64));
      v = fmaxf(v, __shfl_xor(v, 4, 64));
      v = fmaxf(v, __shfl_xor(v, 8, 64));
      float nm = fmaxf(mrun[r], v);
      sc[r] = expf(mrun[r] - nm);
      p0[r] = expf(s0[r] - nm);
      p1[r] = expf(s1[r] - nm);
      float rs = p0[r] + p1[r];
      rs += __shfl_xor(rs, 1, 64);
      rs += __shfl_xor(rs, 2, 64);
      rs += __shfl_xor(rs, 4, 64);
      rs += __shfl_xor(rs, 8, 64);
      lrun[r] = lrun[r] * sc[r] + rs;
      mrun[r] = nm;
    }
    if (__any(sc[0] < 1.f || sc[1] < 1.f || sc[2] < 1.f || sc[3] < 1.f)) {
      f32x4 sv = { sc[0], sc[1], sc[2], sc[3] };
#pragma unroll
      for (int nt = 0; nt < 32; ++nt) acc[nt] *= sv;
    }
#pragma unroll
    for (int r = 0; r < 4; ++r) {
      int row = w * 16 + g * 4 + r;
      lds_p[row * LDP + L]      = f2bf(p0[r]);
      lds_p[row * LDP + 16 + L] = f2bf(p1[r]);
    }
    asm volatile("s_waitcnt lgkmcnt(0)" ::: "memory");
    short8 pf = *(const short8*)&lds_p[(w * 16 + L) * LDP + 8 * g];
#pragma unroll
    for (int nt = 0; nt < 32; ++nt) {
      short8 vf = *(const short8*)&lds_vt[(nt * 16 + L) * LDV + 8 * g];
      acc[nt] = __builtin_amdgcn_mfma_f32_16x16x32_bf16(pf, vf, acc[nt], 0, 0, 0);
    }
  }
  __syncthreads();
  float inv[4];
#pragma unroll
  for (int r = 0; r < 4; ++r) inv[r] = 1.f / lrun[r];
  float* rbuf = (float*)lds_k;
#pragma unroll
  for (int nt = 0; nt < 32; ++nt) {
    f32x4 a = acc[nt];
    float c = fmaxf(fmaxf(a[0] * inv[0], a[1] * inv[1]),
                    fmaxf(a[2] * inv[2], a[3] * inv[3]));
    c = fmaxf(c, __shfl_xor(c, 16, 64));
    c = fmaxf(c, __shfl_xor(c, 32, 64));
    if (g == 0) rbuf[w * 512 + nt * 16 + L] = c;
  }
  __syncthreads();
  for (int j = t; j < 512; j += 256) {
    float v = fmaxf(fmaxf(rbuf[j], rbuf[512 + j]),
                    fmaxf(rbuf[1024 + j], rbuf[1536 + j]));
    atomicMax(&pooled[b * 512 + j], ordf(v));
  }
}

extern "C" __global__ void fc_small(const unsigned* __restrict__ pooled,
                                    const float* __restrict__ fw,
                                    const float* __restrict__ fb,
                                    float* __restrict__ out) {
  int t = threadIdx.x;
  if (t >= 64) return;
  int bb = t >> 1, c = t & 1;
  float s = fb[c];
  for (int e = 0; e < 512; ++e)
    s += unordf(pooled[bb * 512 + e]) * fw[c * 512 + e];
  out[t] = s;
}

extern "C" void kernel_launch(void* const* d_in, const int* in_sizes, int n_in,
                              void* d_out, int out_size, void* d_ws, size_t ws_size,
                              hipStream_t stream) {
  const int* xp    = (const int*)d_in[0];
  const float* emb = (const float*)d_in[1];
  const float* fw  = (const float*)d_in[2];
  const float* fb  = (const float*)d_in[3];
  unsigned* pooled = (unsigned*)d_ws;

  hipMemsetAsync(pooled, 0, 32 * 512 * sizeof(unsigned), stream);  // == -inf

  const size_t need = 65536ull + 2ull * 33554432ull * sizeof(short); // 134.3MB
  if (ws_size >= need) {
    short* Kf = (short*)((char*)d_ws + 65536);
    short* Vf = Kf + 33554432;
    prep_frag<<<dim3(64, 32), 256, 0, stream>>>(xp, emb, Kf, Vf);
    attn2<<<dim3(1024), 256, 0, stream>>>(Kf, Vf, pooled);
  } else {
    attn_fb<<<dim3(32, 32), 256, 0, stream>>>(xp, emb, pooled);
  }
  fc_small<<<1, 64, 0, stream>>>(pooled, fw, fb, (float*)d_out);
}